// Round 3
// baseline (315.653 us; speedup 1.0000x reference)
//
#include <hip/hip_runtime.h>
#include <hip/hip_bf16.h>

// ---- types ----
typedef __attribute__((ext_vector_type(8))) short short8_t;   // 8 x bf16 (4 VGPR)
typedef __attribute__((ext_vector_type(4))) float f32x4;      // MFMA acc

__device__ __forceinline__ short f2bf(float f) {
    union { float f; unsigned u; } v; v.f = f;
    unsigned r = (v.u + 0x7FFFu + ((v.u >> 16) & 1u)) >> 16;  // RNE
    return (short)r;
}

// Geometry: x[8][256][256][256] fp32. u = c in [0,128), v = c in [128,256).
// M = 262144 rows of 256. Per-batch rows = 32768.
// Processed in 4 groups of 2 batches so the fused pass's v re-read hits L3
// (67 MB chunk vs 256 MB Infinity Cache).
#define N_PER_BATCH 8388608.0f
#define LDR 264                  // padded LDS row (bf16): A-reads 2-way banks (free)

// ---------------- kernel 1: per-block partial sums over v ----------------
// grid 512 (2 batches x 256 blocks), block 256.
__global__ __launch_bounds__(256) void stats_partial(const float* __restrict__ x,
                                                     float2* __restrict__ partials,
                                                     int batch0) {
    int bid = blockIdx.x;
    int batch = batch0 + (bid >> 8);
    int blk   = bid & 255;
    const float* base = x + ((size_t)batch << 24) + (1u << 23) + ((size_t)blk << 15);
    int tid = threadIdx.x;
    float s1 = 0.f, s2 = 0.f;
    #pragma unroll
    for (int i = 0; i < 32; ++i) {
        float4 v = *reinterpret_cast<const float4*>(base + (size_t)(i * 256 + tid) * 4);
        s1 += v.x + v.y + v.z + v.w;
        s2 += v.x * v.x + v.y * v.y + v.z * v.z + v.w * v.w;
    }
    #pragma unroll
    for (int off = 32; off; off >>= 1) {
        s1 += __shfl_down(s1, off);
        s2 += __shfl_down(s2, off);
    }
    __shared__ float2 red[4];
    if ((tid & 63) == 0) red[tid >> 6] = make_float2(s1, s2);
    __syncthreads();
    if (tid == 0) {
        float a1 = 0.f, a2 = 0.f;
        #pragma unroll
        for (int w = 0; w < 4; ++w) { a1 += red[w].x; a2 += red[w].y; }
        partials[((size_t)batch << 8) + blk] = make_float2(a1, a2);
    }
}

// ---------------- kernel 1b: finalize per-batch mean/rstd ----------------
// grid 2, block 256.
__global__ __launch_bounds__(256) void stats_final(const float2* __restrict__ partials,
                                                   float2* __restrict__ stats,
                                                   int batch0) {
    int batch = batch0 + blockIdx.x;
    int tid = threadIdx.x;
    float2 p = partials[((size_t)batch << 8) + tid];
    float s1 = p.x, s2 = p.y;
    #pragma unroll
    for (int off = 32; off; off >>= 1) {
        s1 += __shfl_down(s1, off);
        s2 += __shfl_down(s2, off);
    }
    __shared__ float2 red[4];
    if ((tid & 63) == 0) red[tid >> 6] = make_float2(s1, s2);
    __syncthreads();
    if (tid == 0) {
        float a1 = 0.f, a2 = 0.f;
        #pragma unroll
        for (int w = 0; w < 4; ++w) { a1 += red[w].x; a2 += red[w].y; }
        float mean = a1 / N_PER_BATCH;
        float var  = a2 / N_PER_BATCH - mean * mean;
        stats[batch] = make_float2(mean, rsqrtf(var + 1e-5f));
    }
}

// ---------------- kernel 2: fused normalize + GEMM + gate ----------------
// 512 threads = 8 waves, 2 blocks/CU. Wave w holds B-frags for cols
// [w*32, w*32+32) in regs (2 x 16-col sets). Per 16-row tile: block stages
// normalized bf16 v into double-buffered LDS, 16 MFMAs/wave, 4x4
// shuffle-transpose epilogue -> float4 u-load / out-store. 8 tiles/block.
__global__ __launch_bounds__(512, 4) void fused_gemm(const float* __restrict__ x,
                                                     const float* __restrict__ W,
                                                     const float* __restrict__ bias,
                                                     const float2* __restrict__ stats,
                                                     float* __restrict__ out,
                                                     int batch0) {
    __shared__ short vt[2][16 * LDR];   // 16896 B
    const int tid  = threadIdx.x;
    const int wid  = tid >> 6;
    const int lane = tid & 63;
    const int l15  = lane & 15;
    const int l4   = lane >> 4;
    const int q    = l15 & 3;
    const int qg   = l15 >> 2;

    const int bi = batch0 + (blockIdx.x >> 8);      // 256 blocks per batch
    const float2 ms = stats[bi];
    const float mean = ms.x, rstd = ms.y;

    // ---- B fragments: W[col][k], col = wid*32 + c*16 + l15 ----
    short8_t bfrag[2][8];
    #pragma unroll
    for (int c = 0; c < 2; ++c) {
        const float* wbase = W + (size_t)(wid * 32 + c * 16 + l15) * 256 + (l4 << 3);
        #pragma unroll
        for (int kb = 0; kb < 8; ++kb) {
            float4 p0 = *reinterpret_cast<const float4*>(wbase + kb * 32);
            float4 p1 = *reinterpret_cast<const float4*>(wbase + kb * 32 + 4);
            short8_t s;
            s[0] = f2bf(p0.x); s[1] = f2bf(p0.y); s[2] = f2bf(p0.z); s[3] = f2bf(p0.w);
            s[4] = f2bf(p1.x); s[5] = f2bf(p1.y); s[6] = f2bf(p1.z); s[7] = f2bf(p1.w);
            bfrag[c][kb] = s;
        }
    }
    // bias (+1) for post-transpose cols: wid*32 + c*16 + qg*4 + (0..3)
    float4 bq[2];
    #pragma unroll
    for (int c = 0; c < 2; ++c) {
        bq[c] = *reinterpret_cast<const float4*>(bias + wid * 32 + c * 16 + (qg << 2));
        bq[c].x += 1.f; bq[c].y += 1.f; bq[c].z += 1.f; bq[c].w += 1.f;
    }

    // ---- block's rows: 8 tiles x 16 rows = 128 rows within batch bi ----
    const size_t rowb = (size_t)(blockIdx.x & 255) * 128;   // row within batch
    const float* vbase = x + ((size_t)bi << 24) + (1u << 23) + (rowb << 8);
    const float* ubase = x + ((size_t)bi << 24) + (rowb << 8);
    float*       obase = out + (((size_t)bi * 32768 + rowb) << 8);

    // staging role: 1024 float4 per tile / 512 thr = 2 each
    int srow[2], ldsw[2]; size_t goff[2];
    #pragma unroll
    for (int i = 0; i < 2; ++i) {
        int idx4 = tid + (i << 9);
        srow[i] = idx4 >> 6;
        int col = (idx4 & 63) << 2;
        goff[i] = (size_t)srow[i] * 256 + col;
        ldsw[i] = srow[i] * LDR + col;
    }

    // per-wave epilogue offsets: row = l4*4+q, cols = wid*32 + c*16 + qg*4
    size_t eoff[2];
    #pragma unroll
    for (int c = 0; c < 2; ++c)
        eoff[c] = (size_t)(l4 * 4 + q) * 256 + wid * 32 + c * 16 + (qg << 2);

    // A-frag LDS base: row = l15, k-offset = l4*8
    const int aoff = l15 * LDR + (l4 << 3);

    // ---- prologue: stage tile 0 ----
    #pragma unroll
    for (int i = 0; i < 2; ++i) {
        float4 v0 = *reinterpret_cast<const float4*>(vbase + goff[i]);
        short4 s;
        s.x = f2bf((v0.x - mean) * rstd); s.y = f2bf((v0.y - mean) * rstd);
        s.z = f2bf((v0.z - mean) * rstd); s.w = f2bf((v0.w - mean) * rstd);
        *reinterpret_cast<short4*>(&vt[0][ldsw[i]]) = s;
    }
    __syncthreads();

    for (int t = 0; t < 8; ++t) {
        const int cur = t & 1;
        const int tn = (t < 7) ? t + 1 : 7;     // last iter: harmless re-stage
        float4 vn[2];
        #pragma unroll
        for (int i = 0; i < 2; ++i)
            vn[i] = *reinterpret_cast<const float4*>(vbase + ((size_t)tn << 12) + goff[i]);
        float4 u4[2];
        size_t uo[2];
        #pragma unroll
        for (int c = 0; c < 2; ++c) {
            uo[c] = ((size_t)t << 12) + eoff[c];
            u4[c] = *reinterpret_cast<const float4*>(ubase + uo[c]);
        }

        // ---- MFMA over K=256, two 16-col tiles share A ----
        f32x4 acc0 = {0.f, 0.f, 0.f, 0.f};
        f32x4 acc1 = {0.f, 0.f, 0.f, 0.f};
        #pragma unroll
        for (int kb = 0; kb < 8; ++kb) {
            short8_t a = *reinterpret_cast<const short8_t*>(&vt[cur][aoff + kb * 32]);
            acc0 = __builtin_amdgcn_mfma_f32_16x16x32_bf16(a, bfrag[0][kb], acc0, 0, 0, 0);
            acc1 = __builtin_amdgcn_mfma_f32_16x16x32_bf16(a, bfrag[1][kb], acc1, 0, 0, 0);
        }

        // ---- 4x4 transpose within lane quads + epilogue, per col-tile ----
        #pragma unroll
        for (int c = 0; c < 2; ++c) {
            f32x4 acc = c ? acc1 : acc0;
            float v0 = acc[0], v1 = acc[1], v2 = acc[2], v3 = acc[3];
            float s0 = __shfl_xor(v1, 1), s1 = __shfl_xor(v0, 1);
            float s2 = __shfl_xor(v3, 1), s3 = __shfl_xor(v2, 1);
            const bool qb0 = (q & 1);
            float w0 = qb0 ? s0 : v0;
            float w1 = qb0 ? v1 : s1;
            float w2 = qb0 ? s2 : v2;
            float w3 = qb0 ? v3 : s3;
            float t0 = __shfl_xor(w2, 2), t1 = __shfl_xor(w3, 2);
            float t2 = __shfl_xor(w0, 2), t3 = __shfl_xor(w1, 2);
            const bool qb1 = (q & 2);
            float x0 = qb1 ? t0 : w0;
            float x1 = qb1 ? t1 : w1;
            float x2 = qb1 ? w2 : t2;
            float x3 = qb1 ? w3 : t3;
            float4 o;
            o.x = u4[c].x * (x0 + bq[c].x);
            o.y = u4[c].y * (x1 + bq[c].y);
            o.z = u4[c].z * (x2 + bq[c].z);
            o.w = u4[c].w * (x3 + bq[c].w);
            *reinterpret_cast<float4*>(obase + uo[c]) = o;
        }

        // ---- stage next tile into other buffer ----
        #pragma unroll
        for (int i = 0; i < 2; ++i) {
            short4 sn;
            sn.x = f2bf((vn[i].x - mean) * rstd); sn.y = f2bf((vn[i].y - mean) * rstd);
            sn.z = f2bf((vn[i].z - mean) * rstd); sn.w = f2bf((vn[i].w - mean) * rstd);
            *reinterpret_cast<short4*>(&vt[cur ^ 1][ldsw[i]]) = sn;
        }
        __syncthreads();
    }
}

extern "C" void kernel_launch(void* const* d_in, const int* in_sizes, int n_in,
                              void* d_out, int out_size, void* d_ws, size_t ws_size,
                              hipStream_t stream) {
    const float* x    = (const float*)d_in[0];
    const float* W    = (const float*)d_in[1];
    const float* bias = (const float*)d_in[2];
    float* out = (float*)d_out;

    float2* partials = (float2*)d_ws;                       // 8*256 * 8 B
    float2* stats    = (float2*)((char*)d_ws + 32768);      // 8 * 8 B

    for (int g = 0; g < 4; ++g) {
        int b0 = g * 2;
        stats_partial<<<512, 256, 0, stream>>>(x, partials, b0);
        stats_final<<<2, 256, 0, stream>>>(partials, stats, b0);
        fused_gemm<<<512, 512, 0, stream>>>(x, W, bias, stats, out, b0);
    }
}

// Round 4
// 249.008 us; speedup vs baseline: 1.2676x; 1.2676x over previous
//
#include <hip/hip_runtime.h>
#include <hip/hip_bf16.h>

// ---- types ----
typedef __attribute__((ext_vector_type(8))) short short8_t;   // 8 x bf16 (4 VGPR)
typedef __attribute__((ext_vector_type(4))) float f32x4;      // MFMA acc

__device__ __forceinline__ short f2bf(float f) {
    union { float f; unsigned u; } v; v.f = f;
    unsigned r = (v.u + 0x7FFFu + ((v.u >> 16) & 1u)) >> 16;  // RNE
    return (short)r;
}

// Geometry: x[8][256][256][256] fp32. u = c in [0,128), v = c in [128,256).
// M = 262144 rows of 256. Per-batch rows = 32768.
#define N_PER_BATCH 8388608.0f
#define LDR 264                  // padded LDS row (bf16): A-reads 2-way banks (free)

// ---------------- kernel 1: per-block partial sums over v ----------------
// grid 2048 (256 blocks/batch), block 256.
__global__ __launch_bounds__(256) void stats_partial(const float* __restrict__ x,
                                                     float2* __restrict__ partials) {
    int bid = blockIdx.x;
    int batch = bid >> 8;
    int blk   = bid & 255;
    const float* base = x + ((size_t)batch << 24) + (1u << 23) + ((size_t)blk << 15);
    int tid = threadIdx.x;
    float s1 = 0.f, s2 = 0.f;
    #pragma unroll
    for (int i = 0; i < 32; ++i) {
        float4 v = *reinterpret_cast<const float4*>(base + (size_t)(i * 256 + tid) * 4);
        s1 += v.x + v.y + v.z + v.w;
        s2 += v.x * v.x + v.y * v.y + v.z * v.z + v.w * v.w;
    }
    #pragma unroll
    for (int off = 32; off; off >>= 1) {
        s1 += __shfl_down(s1, off);
        s2 += __shfl_down(s2, off);
    }
    __shared__ float2 red[4];
    if ((tid & 63) == 0) red[tid >> 6] = make_float2(s1, s2);
    __syncthreads();
    if (tid == 0) {
        float a1 = 0.f, a2 = 0.f;
        #pragma unroll
        for (int w = 0; w < 4; ++w) { a1 += red[w].x; a2 += red[w].y; }
        partials[bid] = make_float2(a1, a2);
    }
}

// ---------------- kernel 1b: finalize per-batch mean/rstd ----------------
__global__ __launch_bounds__(256) void stats_final(const float2* __restrict__ partials,
                                                   float2* __restrict__ stats) {
    int batch = blockIdx.x;
    int tid = threadIdx.x;
    float2 p = partials[(batch << 8) + tid];
    float s1 = p.x, s2 = p.y;
    #pragma unroll
    for (int off = 32; off; off >>= 1) {
        s1 += __shfl_down(s1, off);
        s2 += __shfl_down(s2, off);
    }
    __shared__ float2 red[4];
    if ((tid & 63) == 0) red[tid >> 6] = make_float2(s1, s2);
    __syncthreads();
    if (tid == 0) {
        float a1 = 0.f, a2 = 0.f;
        #pragma unroll
        for (int w = 0; w < 4; ++w) { a1 += red[w].x; a2 += red[w].y; }
        float mean = a1 / N_PER_BATCH;
        float var  = a2 / N_PER_BATCH - mean * mean;
        stats[batch] = make_float2(mean, rsqrtf(var + 1e-5f));
    }
}

// ---------------- kernel 2: fused normalize + GEMM + gate ----------------
// 512 threads = 8 waves; __launch_bounds__(512,4) caps VGPR<=128 => 2 blocks/CU.
// Grid 512 = exactly 2 blocks/CU, no tail. Wave w holds B-frags for cols
// [w*32, w*32+32) in regs. 32 tiles of 16 rows per block; per tile: block
// stages normalized bf16 v into double-buffered LDS (reg-staged), 16
// MFMAs/wave, 4x4 shuffle-transpose epilogue -> float4 u-load / out-store.
__global__ __launch_bounds__(512, 4) void fused_gemm(const float* __restrict__ x,
                                                     const float* __restrict__ W,
                                                     const float* __restrict__ bias,
                                                     const float2* __restrict__ stats,
                                                     float* __restrict__ out) {
    __shared__ short vt[2][16 * LDR];   // 16896 B
    const int tid  = threadIdx.x;
    const int wid  = tid >> 6;
    const int lane = tid & 63;
    const int l15  = lane & 15;
    const int l4   = lane >> 4;
    const int q    = l15 & 3;
    const int qg   = l15 >> 2;

    const int bi = blockIdx.x >> 6;          // 64 blocks per batch
    const float2 ms = stats[bi];
    const float mean = ms.x, rstd = ms.y;

    // ---- B fragments: W[col][k], col = wid*32 + c*16 + l15 ----
    short8_t bfrag[2][8];
    #pragma unroll
    for (int c = 0; c < 2; ++c) {
        const float* wbase = W + (size_t)(wid * 32 + c * 16 + l15) * 256 + (l4 << 3);
        #pragma unroll
        for (int kb = 0; kb < 8; ++kb) {
            float4 p0 = *reinterpret_cast<const float4*>(wbase + kb * 32);
            float4 p1 = *reinterpret_cast<const float4*>(wbase + kb * 32 + 4);
            short8_t s;
            s[0] = f2bf(p0.x); s[1] = f2bf(p0.y); s[2] = f2bf(p0.z); s[3] = f2bf(p0.w);
            s[4] = f2bf(p1.x); s[5] = f2bf(p1.y); s[6] = f2bf(p1.z); s[7] = f2bf(p1.w);
            bfrag[c][kb] = s;
        }
    }
    // bias (+1) for post-transpose cols: wid*32 + c*16 + qg*4 + (0..3)
    float4 bq[2];
    #pragma unroll
    for (int c = 0; c < 2; ++c) {
        bq[c] = *reinterpret_cast<const float4*>(bias + wid * 32 + c * 16 + (qg << 2));
        bq[c].x += 1.f; bq[c].y += 1.f; bq[c].z += 1.f; bq[c].w += 1.f;
    }

    // ---- block's rows: 32 tiles x 16 rows = 512 rows within batch bi ----
    const size_t rowb = (size_t)(blockIdx.x & 63) * 512;    // row within batch
    const float* vbase = x + ((size_t)bi << 24) + (1u << 23) + (rowb << 8);
    const float* ubase = x + ((size_t)bi << 24) + (rowb << 8);
    float*       obase = out + (((size_t)bi * 32768 + rowb) << 8);

    // staging role: 1024 float4 per tile / 512 thr = 2 each
    int srow[2], ldsw[2]; size_t goff[2];
    #pragma unroll
    for (int i = 0; i < 2; ++i) {
        int idx4 = tid + (i << 9);
        srow[i] = idx4 >> 6;
        int col = (idx4 & 63) << 2;
        goff[i] = (size_t)srow[i] * 256 + col;
        ldsw[i] = srow[i] * LDR + col;
    }

    // per-wave epilogue offsets: row = l4*4+q, cols = wid*32 + c*16 + qg*4
    size_t eoff[2];
    #pragma unroll
    for (int c = 0; c < 2; ++c)
        eoff[c] = (size_t)(l4 * 4 + q) * 256 + wid * 32 + c * 16 + (qg << 2);

    // A-frag LDS base: row = l15, k-offset = l4*8
    const int aoff = l15 * LDR + (l4 << 3);

    // ---- prologue: stage tile 0 ----
    #pragma unroll
    for (int i = 0; i < 2; ++i) {
        float4 v0 = *reinterpret_cast<const float4*>(vbase + goff[i]);
        short4 s;
        s.x = f2bf((v0.x - mean) * rstd); s.y = f2bf((v0.y - mean) * rstd);
        s.z = f2bf((v0.z - mean) * rstd); s.w = f2bf((v0.w - mean) * rstd);
        *reinterpret_cast<short4*>(&vt[0][ldsw[i]]) = s;
    }
    __syncthreads();

    for (int t = 0; t < 32; ++t) {
        const int cur = t & 1;
        const int tn = (t < 31) ? t + 1 : 31;   // last iter: harmless re-stage
        float4 vn[2];
        #pragma unroll
        for (int i = 0; i < 2; ++i)
            vn[i] = *reinterpret_cast<const float4*>(vbase + ((size_t)tn << 12) + goff[i]);
        float4 u4[2];
        size_t uo[2];
        #pragma unroll
        for (int c = 0; c < 2; ++c) {
            uo[c] = ((size_t)t << 12) + eoff[c];
            u4[c] = *reinterpret_cast<const float4*>(ubase + uo[c]);
        }

        // ---- MFMA over K=256, two 16-col tiles share A ----
        f32x4 acc0 = {0.f, 0.f, 0.f, 0.f};
        f32x4 acc1 = {0.f, 0.f, 0.f, 0.f};
        #pragma unroll
        for (int kb = 0; kb < 8; ++kb) {
            short8_t a = *reinterpret_cast<const short8_t*>(&vt[cur][aoff + kb * 32]);
            acc0 = __builtin_amdgcn_mfma_f32_16x16x32_bf16(a, bfrag[0][kb], acc0, 0, 0, 0);
            acc1 = __builtin_amdgcn_mfma_f32_16x16x32_bf16(a, bfrag[1][kb], acc1, 0, 0, 0);
        }

        // ---- 4x4 transpose within lane quads + epilogue, per col-tile ----
        #pragma unroll
        for (int c = 0; c < 2; ++c) {
            f32x4 acc = c ? acc1 : acc0;
            float v0 = acc[0], v1 = acc[1], v2 = acc[2], v3 = acc[3];
            float s0 = __shfl_xor(v1, 1), s1 = __shfl_xor(v0, 1);
            float s2 = __shfl_xor(v3, 1), s3 = __shfl_xor(v2, 1);
            const bool qb0 = (q & 1);
            float w0 = qb0 ? s0 : v0;
            float w1 = qb0 ? v1 : s1;
            float w2 = qb0 ? s2 : v2;
            float w3 = qb0 ? v3 : s3;
            float t0 = __shfl_xor(w2, 2), t1 = __shfl_xor(w3, 2);
            float t2 = __shfl_xor(w0, 2), t3 = __shfl_xor(w1, 2);
            const bool qb1 = (q & 2);
            float x0 = qb1 ? t0 : w0;
            float x1 = qb1 ? t1 : w1;
            float x2 = qb1 ? w2 : t2;
            float x3 = qb1 ? w3 : t3;
            float4 o;
            o.x = u4[c].x * (x0 + bq[c].x);
            o.y = u4[c].y * (x1 + bq[c].y);
            o.z = u4[c].z * (x2 + bq[c].z);
            o.w = u4[c].w * (x3 + bq[c].w);
            *reinterpret_cast<float4*>(obase + uo[c]) = o;
        }

        // ---- stage next tile into other buffer ----
        #pragma unroll
        for (int i = 0; i < 2; ++i) {
            short4 sn;
            sn.x = f2bf((vn[i].x - mean) * rstd); sn.y = f2bf((vn[i].y - mean) * rstd);
            sn.z = f2bf((vn[i].z - mean) * rstd); sn.w = f2bf((vn[i].w - mean) * rstd);
            *reinterpret_cast<short4*>(&vt[cur ^ 1][ldsw[i]]) = sn;
        }
        __syncthreads();
    }
}

extern "C" void kernel_launch(void* const* d_in, const int* in_sizes, int n_in,
                              void* d_out, int out_size, void* d_ws, size_t ws_size,
                              hipStream_t stream) {
    const float* x    = (const float*)d_in[0];
    const float* W    = (const float*)d_in[1];
    const float* bias = (const float*)d_in[2];
    float* out = (float*)d_out;

    float2* partials = (float2*)d_ws;                       // 2048 * 8 B
    float2* stats    = (float2*)((char*)d_ws + 16384);      // 8 * 8 B

    stats_partial<<<2048, 256, 0, stream>>>(x, partials);
    stats_final<<<8, 256, 0, stream>>>(partials, stats);
    fused_gemm<<<512, 512, 0, stream>>>(x, W, bias, stats, out);
}

// Round 5
// 213.300 us; speedup vs baseline: 1.4799x; 1.1674x over previous
//
#include <hip/hip_runtime.h>
#include <hip/hip_bf16.h>

// ---- types ----
typedef __attribute__((ext_vector_type(8))) short short8_t;   // 8 x bf16 (4 VGPR)
typedef __attribute__((ext_vector_type(4))) float f32x4;      // MFMA acc

__device__ __forceinline__ short f2bf(float f) {
    union { float f; unsigned u; } v; v.f = f;
    unsigned r = (v.u + 0x7FFFu + ((v.u >> 16) & 1u)) >> 16;  // RNE
    return (short)r;
}

// Geometry: x[8][256][256][256] fp32. u = c in [0,128), v = c in [128,256).
// M = 262144 rows of 256. Per-batch rows = 32768.
#define N_PER_BATCH 8388608.0f
#define LDR 264                  // padded LDS row (bf16): A-reads 2-way banks (free)

// ---------------- kernel 1: per-block partial sums over v ----------------
__global__ __launch_bounds__(256) void stats_partial(const float* __restrict__ x,
                                                     float2* __restrict__ partials) {
    int bid = blockIdx.x;
    int batch = bid >> 8;
    int blk   = bid & 255;
    const float* base = x + ((size_t)batch << 24) + (1u << 23) + ((size_t)blk << 15);
    int tid = threadIdx.x;
    float s1 = 0.f, s2 = 0.f;
    #pragma unroll
    for (int i = 0; i < 32; ++i) {
        float4 v = *reinterpret_cast<const float4*>(base + (size_t)(i * 256 + tid) * 4);
        s1 += v.x + v.y + v.z + v.w;
        s2 += v.x * v.x + v.y * v.y + v.z * v.z + v.w * v.w;
    }
    #pragma unroll
    for (int off = 32; off; off >>= 1) {
        s1 += __shfl_down(s1, off);
        s2 += __shfl_down(s2, off);
    }
    __shared__ float2 red[4];
    if ((tid & 63) == 0) red[tid >> 6] = make_float2(s1, s2);
    __syncthreads();
    if (tid == 0) {
        float a1 = 0.f, a2 = 0.f;
        #pragma unroll
        for (int w = 0; w < 4; ++w) { a1 += red[w].x; a2 += red[w].y; }
        partials[bid] = make_float2(a1, a2);
    }
}

// ---------------- kernel 1b: finalize per-batch mean/rstd ----------------
__global__ __launch_bounds__(256) void stats_final(const float2* __restrict__ partials,
                                                   float2* __restrict__ stats) {
    int batch = blockIdx.x;
    int tid = threadIdx.x;
    float2 p = partials[(batch << 8) + tid];
    float s1 = p.x, s2 = p.y;
    #pragma unroll
    for (int off = 32; off; off >>= 1) {
        s1 += __shfl_down(s1, off);
        s2 += __shfl_down(s2, off);
    }
    __shared__ float2 red[4];
    if ((tid & 63) == 0) red[tid >> 6] = make_float2(s1, s2);
    __syncthreads();
    if (tid == 0) {
        float a1 = 0.f, a2 = 0.f;
        #pragma unroll
        for (int w = 0; w < 4; ++w) { a1 += red[w].x; a2 += red[w].y; }
        float mean = a1 / N_PER_BATCH;
        float var  = a2 / N_PER_BATCH - mean * mean;
        stats[batch] = make_float2(mean, rsqrtf(var + 1e-5f));
    }
}

// ---------------- kernel 2: fused normalize + GEMM + gate ----------------
// 1024 thr = 16 waves, 1 block/CU. Wave w owns cols [w*16, w*16+16) (32 VGPR
// B-frags). Per 16-row tile: reg-staged normalized bf16 v -> double-buffered
// LDS; 8 MFMAs/wave; quad-transpose epilogue -> float4 u-load / out-store.
// MLP: v prefetched 2 tiles ahead, u 1 tile ahead; raw s_barrier with ONLY
// lgkmcnt(0) (no vmcnt drain) keeps ~32 KB/CU of global loads in flight
// across the per-tile barrier.
__global__ __launch_bounds__(1024, 4) void fused_gemm(const float* __restrict__ x,
                                                      const float* __restrict__ W,
                                                      const float* __restrict__ bias,
                                                      const float2* __restrict__ stats,
                                                      float* __restrict__ out) {
    __shared__ short vt[2][16 * LDR];   // 16896 B
    const int tid  = threadIdx.x;
    const int wid  = tid >> 6;
    const int lane = tid & 63;
    const int l15  = lane & 15;
    const int l4   = lane >> 4;
    const int q    = l15 & 3;
    const int qg   = l15 >> 2;

    const int bi = blockIdx.x >> 5;          // 32 blocks per batch
    const float2 ms = stats[bi];
    const float mean = ms.x, rstd = ms.y;

    // ---- B fragments: W[col][k], col = wid*16 + l15, k = kb*32 + l4*8 + j ----
    short8_t bfrag[8];
    {
        const float* wbase = W + (size_t)(wid * 16 + l15) * 256 + (l4 << 3);
        #pragma unroll
        for (int kb = 0; kb < 8; ++kb) {
            float4 p0 = *reinterpret_cast<const float4*>(wbase + kb * 32);
            float4 p1 = *reinterpret_cast<const float4*>(wbase + kb * 32 + 4);
            short8_t s;
            s[0] = f2bf(p0.x); s[1] = f2bf(p0.y); s[2] = f2bf(p0.z); s[3] = f2bf(p0.w);
            s[4] = f2bf(p1.x); s[5] = f2bf(p1.y); s[6] = f2bf(p1.z); s[7] = f2bf(p1.w);
            bfrag[kb] = s;
        }
    }
    // bias (+1) for post-transpose cols: wid*16 + qg*4 + (0..3)
    float4 bq = *reinterpret_cast<const float4*>(bias + wid * 16 + (qg << 2));
    bq.x += 1.f; bq.y += 1.f; bq.z += 1.f; bq.w += 1.f;

    // ---- block's rows: 64 tiles x 16 rows = 1024 rows within batch bi ----
    const size_t rowb = (size_t)(blockIdx.x & 31) * 1024;
    const float* vbase = x + ((size_t)bi << 24) + (1u << 23) + (rowb << 8);
    const float* ubase = x + ((size_t)bi << 24) + (rowb << 8);
    float*       obase = out + (((size_t)bi * 32768 + rowb) << 8);

    // staging role: 1024 float4 per tile / 1024 thr = 1 each
    const int   srow = tid >> 6;
    const int   scol = (tid & 63) << 2;
    const size_t goff = (size_t)srow * 256 + scol;
    const int   ldsw = srow * LDR + scol;

    // per-wave epilogue offset: row = l4*4+q, cols = wid*16 + qg*4
    const size_t eoff = (size_t)(l4 * 4 + q) * 256 + wid * 16 + (qg << 2);

    // A-frag LDS base: row = l15, k-offset = l4*8
    const int aoff = l15 * LDR + (l4 << 3);

    const int nt = 64;

    // ---- prologue: stage tile 0; start v(1), u(0) ----
    float4 v0 = *reinterpret_cast<const float4*>(vbase + goff);
    float4 vA = *reinterpret_cast<const float4*>(vbase + (1ull << 12) + goff);  // v(1)
    float4 uA = *reinterpret_cast<const float4*>(ubase + eoff);                 // u(0)
    {
        short4 s;
        s.x = f2bf((v0.x - mean) * rstd); s.y = f2bf((v0.y - mean) * rstd);
        s.z = f2bf((v0.z - mean) * rstd); s.w = f2bf((v0.w - mean) * rstd);
        *reinterpret_cast<short4*>(&vt[0][ldsw]) = s;
    }
    asm volatile("s_waitcnt lgkmcnt(0)" ::: "memory");
    __builtin_amdgcn_s_barrier();

    for (int t = 0; t < nt; ++t) {
        const int cur = t & 1;
        const int t2 = (t + 2 < nt) ? t + 2 : nt - 1;
        const int t1 = (t + 1 < nt) ? t + 1 : nt - 1;
        // issue deep prefetches first (stay in flight across the barrier)
        float4 vB = *reinterpret_cast<const float4*>(vbase + ((size_t)t2 << 12) + goff);
        float4 uB = *reinterpret_cast<const float4*>(ubase + ((size_t)t1 << 12) + eoff);

        // ---- MFMA over K=256 ----
        f32x4 acc = {0.f, 0.f, 0.f, 0.f};
        #pragma unroll
        for (int kb = 0; kb < 8; ++kb) {
            short8_t a = *reinterpret_cast<const short8_t*>(&vt[cur][aoff + kb * 32]);
            acc = __builtin_amdgcn_mfma_f32_16x16x32_bf16(a, bfrag[kb], acc, 0, 0, 0);
        }

        // ---- 4x4 transpose within lane quads: reg r <-> lane q ----
        float a0 = acc[0], a1 = acc[1], a2 = acc[2], a3 = acc[3];
        float s0 = __shfl_xor(a1, 1), s1 = __shfl_xor(a0, 1);
        float s2 = __shfl_xor(a3, 1), s3 = __shfl_xor(a2, 1);
        const bool qb0 = (q & 1);
        float w0 = qb0 ? s0 : a0;
        float w1 = qb0 ? a1 : s1;
        float w2 = qb0 ? s2 : a2;
        float w3 = qb0 ? a3 : s3;
        float t0 = __shfl_xor(w2, 2), t1v = __shfl_xor(w3, 2);
        float t2v = __shfl_xor(w0, 2), t3 = __shfl_xor(w1, 2);
        const bool qb1 = (q & 2);
        float x0 = qb1 ? t0 : w0;
        float x1 = qb1 ? t1v : w1;
        float x2 = qb1 ? w2 : t2v;
        float x3 = qb1 ? w3 : t3;

        // ---- epilogue: out = u * (y + b + 1) ----
        const size_t uo = ((size_t)t << 12) + eoff;
        float4 o;
        o.x = uA.x * (x0 + bq.x);
        o.y = uA.y * (x1 + bq.y);
        o.z = uA.z * (x2 + bq.z);
        o.w = uA.w * (x3 + bq.w);
        *reinterpret_cast<float4*>(obase + uo) = o;

        // ---- stage tile t+1 (vA) into other buffer ----
        short4 sn;
        sn.x = f2bf((vA.x - mean) * rstd); sn.y = f2bf((vA.y - mean) * rstd);
        sn.z = f2bf((vA.z - mean) * rstd); sn.w = f2bf((vA.w - mean) * rstd);
        *reinterpret_cast<short4*>(&vt[cur ^ 1][ldsw]) = sn;

        // raw barrier: drain LDS only, keep global loads in flight
        asm volatile("s_waitcnt lgkmcnt(0)" ::: "memory");
        __builtin_amdgcn_s_barrier();

        vA = vB; uA = uB;
    }
}

extern "C" void kernel_launch(void* const* d_in, const int* in_sizes, int n_in,
                              void* d_out, int out_size, void* d_ws, size_t ws_size,
                              hipStream_t stream) {
    const float* x    = (const float*)d_in[0];
    const float* W    = (const float*)d_in[1];
    const float* bias = (const float*)d_in[2];
    float* out = (float*)d_out;

    float2* partials = (float2*)d_ws;                       // 2048 * 8 B
    float2* stats    = (float2*)((char*)d_ws + 16384);      // 8 * 8 B

    stats_partial<<<2048, 256, 0, stream>>>(x, partials);
    stats_final<<<8, 256, 0, stream>>>(partials, stats);
    fused_gemm<<<256, 1024, 0, stream>>>(x, W, bias, stats, out);
}